// Round 7
// baseline (85.614 us; speedup 1.0000x reference)
//
#include <hip/hip_runtime.h>
#include <math.h>

// Problem constants
#define NBATCH 4
#define NCLS   19
#define HWDIM  512
#define HW     (512 * 512)      // 262144
#define PH     171              // pooled H=W
#define PHP    176              // padded row stride (16B-aligned rows)
#define PP2A   (171 * 176)      // 30096 floats per (n,c) plane
#define NHW    169              // PH - radius + 1
#define MM     (169 * 169)      // 28561
#define NBAND  11               // stage2 y-bands per z-half
#define NSTRIP 43               // ceil(169/4) strips of 4 positions
#define ZS     2                // stage2 z-split

typedef float f4 __attribute__((ext_vector_type(4)));
typedef float f2 __attribute__((ext_vector_type(2)));

// ---------------------------------------------------------------------------
// Stage 1: fused softmax + one-hot + 3x3/stride-3 avg-pool (pad=1, /9).
// One block per (n, pooled-row ph); thread = input column. ALL 57 cls loads +
// 3 label loads hoisted before any math (57 outstanding loads hide latency).
// __expf (native v_exp_f32). x-pool via LDS in 2 rounds of 10 classes.
// ---------------------------------------------------------------------------
__global__ __launch_bounds__(512) void stage1_pool(
    const float* __restrict__ cls, const int* __restrict__ label,
    float* __restrict__ P, float* __restrict__ L) {
  int n  = blockIdx.x / PH;
  int ph = blockIdx.x - n * PH;
  int col = threadIdx.x;  // input column 0..511

  // ---- hoisted loads (only ph==0 has an invalid row: r=-1) ----
  float vv[3][NCLS];
  int lbs[3];
#pragma unroll
  for (int i = 0; i < 3; ++i) {
    int r = 3 * ph - 1 + i;
    bool ok = (r >= 0) && (r < HWDIM);  // wave-uniform branch
    if (ok) {
      lbs[i] = label[((size_t)n * HWDIM + r) * HWDIM + col];
      const float* base = cls + (size_t)n * NCLS * HW + (size_t)r * HWDIM + col;
#pragma unroll
      for (int c = 0; c < NCLS; ++c) vv[i][c] = base[(size_t)c * HW];
    } else {
      lbs[i] = -1;
#pragma unroll
      for (int c = 0; c < NCLS; ++c) vv[i][c] = 0.f;
    }
  }

  // ---- per-row softmax + masked accumulate (math unconditional; zeros are
  //      harmless: lb=-1 -> mask 0 -> no contribution) ----
  float accP[NCLS], accL[NCLS];
#pragma unroll
  for (int c = 0; c < NCLS; ++c) { accP[c] = 0.f; accL[c] = 0.f; }
#pragma unroll
  for (int i = 0; i < 3; ++i) {
    int lb = lbs[i];
    float mx = vv[i][0];
#pragma unroll
    for (int c = 1; c < NCLS; ++c) mx = fmaxf(mx, vv[i][c]);
    float se = 0.f;
    float ex[NCLS];
#pragma unroll
    for (int c = 0; c < NCLS; ++c) {
      ex[c] = __expf(vv[i][c] - mx);
      se += ex[c];
    }
    float m = (lb >= 0 && lb < NCLS) ? 1.f : 0.f;
    float inv = m / se;
#pragma unroll
    for (int c = 0; c < NCLS; ++c) {
      accP[c] += ex[c] * inv;
      accL[c] += (lb == c) ? 1.f : 0.f;  // compile-time index
    }
  }

  // ---- x-pool via LDS, 2 rounds of 10 classes ----
  __shared__ float xbP[10][516];
  __shared__ float xbL[10][516];
  const float inv9 = 1.f / 9.f;
#pragma unroll
  for (int c0 = 0; c0 < NCLS; c0 += 10) {
#pragma unroll
    for (int cc = 0; cc < 10; ++cc) {
      if (c0 + cc < NCLS) {
        xbP[cc][1 + col] = accP[(c0 + cc) < NCLS ? (c0 + cc) : 0];
        xbL[cc][1 + col] = accL[(c0 + cc) < NCLS ? (c0 + cc) : 0];
        if (col == 0) { xbP[cc][0] = 0.f; xbL[cc][0] = 0.f; }
      }
    }
    __syncthreads();
    if (col < PH) {
      int pw = col;
#pragma unroll
      for (int cc = 0; cc < 10; ++cc) {
        if (c0 + cc < NCLS) {
          int c = c0 + cc;
          float sP = xbP[cc][3 * pw] + xbP[cc][3 * pw + 1] + xbP[cc][3 * pw + 2];
          float sL = xbL[cc][3 * pw] + xbL[cc][3 * pw + 1] + xbL[cc][3 * pw + 2];
          size_t o = ((size_t)(n * NCLS + c)) * PP2A + (size_t)ph * PHP + pw;
          P[o] = sP * inv9;
          L[o] = sL * inv9;
        }
      }
    } else if (col < PHP) {
      // zero pad columns 171..175 so stage2 vector loads see zeros
#pragma unroll
      for (int cc = 0; cc < 10; ++cc) {
        if (c0 + cc < NCLS) {
          int c = c0 + cc;
          size_t o = ((size_t)(n * NCLS + c)) * PP2A + (size_t)ph * PHP + col;
          P[o] = 0.f;
          L[o] = 0.f;
        }
      }
    }
    __syncthreads();
  }
}

// ---------------------------------------------------------------------------
// Stage 2: per (n,c) raw-moment accumulation over M=169^2 window positions.
// Strip of 4 positions per thread; sliding window in y with prefetch-1-row.
// Grid (76, 3 parts, ZS z-halves) = 456 blocks -> ~3.6 waves/SIMD TLP.
// Tail-strip guard hoisted OUT of y-loop (full path vs 1-position path).
// Epilogue: 3-level shuffle (8 partials/wave) + 64-row LDS reduce.
// Record layout (z*76+nc)*192:
//   [0..8] sum la | [9..17] sum pr | [18..62] la*la ut45 | [63..107] pr*pr ut45
//   [108..188] pr[d]*la[e] (81) | [190..191] (double) logdet (z=0 rec only)
// ---------------------------------------------------------------------------
template <int PART, int NA, int POS>
__device__ __forceinline__ void fma_pos(float (&acc)[NA],
                                        const float (&wp)[18],
                                        const float (&wl)[18]) {
  if (PART == 0) {
#pragma unroll
    for (int d = 0; d < 9; ++d) {
      acc[d]     += wl[(d / 3) * 6 + POS + (d % 3)];
      acc[9 + d] += wp[(d / 3) * 6 + POS + (d % 3)];
    }
    int k = 18;
#pragma unroll
    for (int d = 0; d < 9; ++d)
#pragma unroll
      for (int e = d; e < 9; ++e) {
        acc[k] += wl[(d / 3) * 6 + POS + (d % 3)] *
                  wl[(e / 3) * 6 + POS + (e % 3)];
        ++k;
      }
  } else if (PART == 1) {
    int k = 0;
#pragma unroll
    for (int d = 0; d < 9; ++d)
#pragma unroll
      for (int e = d; e < 9; ++e) {
        acc[k] += wp[(d / 3) * 6 + POS + (d % 3)] *
                  wp[(e / 3) * 6 + POS + (e % 3)];
        ++k;
      }
  } else {
#pragma unroll
    for (int d = 0; d < 9; ++d)
#pragma unroll
      for (int e = 0; e < 9; ++e)
        acc[d * 9 + e] += wp[(d / 3) * 6 + POS + (d % 3)] *
                          wl[(e / 3) * 6 + POS + (e % 3)];
  }
}

template <int PART>
__device__ __forceinline__ void mom_body(
    const float* __restrict__ Pp, const float* __restrict__ Lp,
    float* __restrict__ covp, int rec, int z, float* red) {
  constexpr int NA  = (PART == 0) ? 63 : (PART == 1 ? 45 : 81);
  constexpr int OFF = (PART == 0) ? 0  : (PART == 1 ? 63 : 108);

  float acc[NA];
#pragma unroll
  for (int k = 0; k < NA; ++k) acc[k] = 0.f;

  int tid = threadIdx.x;
  if (tid < NSTRIP * NBAND) {
    int b  = tid / NSTRIP;
    int s  = tid - b * NSTRIP;
    int x0 = 4 * s;                       // 0..168
    int zr0 = (NHW * z) / ZS;
    int zr1 = (NHW * (z + 1)) / ZS;
    int zr  = zr1 - zr0;
    int y0 = zr0 + (zr * b) / NBAND;
    int y1 = zr0 + (zr * (b + 1)) / NBAND;

    float wp[18], wl[18];
    // prime rows y0..y0+2
#pragma unroll
    for (int r = 0; r < 3; ++r) {
      const float* rp = Pp + (y0 + r) * PHP + x0;
      *(f4*)&wp[r * 6]     = *(const f4*)rp;
      *(f2*)&wp[r * 6 + 4] = *(const f2*)(rp + 4);
      if (PART != 1) {
        const float* rl = Lp + (y0 + r) * PHP + x0;
        *(f4*)&wl[r * 6]     = *(const f4*)rl;
        *(f2*)&wl[r * 6 + 4] = *(const f2*)(rl + 4);
      }
    }

    if (x0 + 4 <= NHW) {  // full strip: 4 positions, no guards in loop
      for (int y = y0; y < y1; ++y) {
        int yn = (y + 3 <= PH - 1) ? (y + 3) : (PH - 1);
        const float* rp = Pp + yn * PHP + x0;
        f4 tp4 = *(const f4*)rp;
        f2 tp2 = *(const f2*)(rp + 4);
        f4 tl4; f2 tl2;
        if (PART != 1) {
          const float* rl = Lp + yn * PHP + x0;
          tl4 = *(const f4*)rl;
          tl2 = *(const f2*)(rl + 4);
        }
        fma_pos<PART, NA, 0>(acc, wp, wl);
        fma_pos<PART, NA, 1>(acc, wp, wl);
        fma_pos<PART, NA, 2>(acc, wp, wl);
        fma_pos<PART, NA, 3>(acc, wp, wl);
#pragma unroll
        for (int t = 0; t < 12; ++t) {
          wp[t] = wp[t + 6];
          if (PART != 1) wl[t] = wl[t + 6];
        }
        *(f4*)&wp[12] = tp4;
        *(f2*)&wp[16] = tp2;
        if (PART != 1) { *(f4*)&wl[12] = tl4; *(f2*)&wl[16] = tl2; }
      }
    } else {  // tail strip (x0=168): exactly 1 valid position
      for (int y = y0; y < y1; ++y) {
        int yn = (y + 3 <= PH - 1) ? (y + 3) : (PH - 1);
        const float* rp = Pp + yn * PHP + x0;
        f4 tp4 = *(const f4*)rp;
        f2 tp2 = *(const f2*)(rp + 4);
        f4 tl4; f2 tl2;
        if (PART != 1) {
          const float* rl = Lp + yn * PHP + x0;
          tl4 = *(const f4*)rl;
          tl2 = *(const f2*)(rl + 4);
        }
        fma_pos<PART, NA, 0>(acc, wp, wl);
#pragma unroll
        for (int t = 0; t < 12; ++t) {
          wp[t] = wp[t + 6];
          if (PART != 1) wl[t] = wl[t + 6];
        }
        *(f4*)&wp[12] = tp4;
        *(f2*)&wp[16] = tp2;
        if (PART != 1) { *(f4*)&wl[12] = tl4; *(f2*)&wl[16] = tl2; }
      }
    }
  }

  // 3-level shuffle (8 partials/wave) -> 64-row LDS reduce
  int lane = threadIdx.x & 63;
  int wid  = threadIdx.x >> 6;  // 8 waves
#pragma unroll
  for (int k = 0; k < NA; ++k) {
    float v = acc[k];
    v += __shfl_down(v, 32, 64);
    v += __shfl_down(v, 16, 64);
    v += __shfl_down(v, 8, 64);
    if (lane < 8) red[(wid * 8 + lane) * 84 + k] = v;
  }
  __syncthreads();
  if (tid < NA) {
    float sm = 0.f;
#pragma unroll
    for (int w = 0; w < 64; ++w) sm += red[w * 84 + tid];
    covp[(size_t)rec * 192 + OFF + tid] = sm;
  }
}

__global__ __launch_bounds__(512) void stage2_mom(
    const float* __restrict__ P, const float* __restrict__ L,
    float* __restrict__ covp) {
  __shared__ float red[64 * 84];  // 21.5 KB
  int nc = blockIdx.x;
  int z  = blockIdx.z;
  int rec = z * (NBATCH * NCLS) + nc;
  const float* Pp = P + (size_t)nc * PP2A;
  const float* Lp = L + (size_t)nc * PP2A;
  if (blockIdx.y == 0)      mom_body<0>(Pp, Lp, covp, rec, z, red);
  else if (blockIdx.y == 1) mom_body<1>(Pp, Lp, covp, rec, z, red);
  else                      mom_body<2>(Pp, Lp, covp, rec, z, red);
}

// ---------------------------------------------------------------------------
// Stage 3: one 64-thread block per (n,c). Sums the ZS partials, builds
// covariances in fp64 in LDS, Cholesky(la_cov+1e-5 I), triangular solve,
// Schur complement + 1e-6 I, Cholesky logdet -> covp[nc*192 + 190..191].
// ---------------------------------------------------------------------------
__global__ __launch_bounds__(64) void stage3_rmi(float* __restrict__ covp) {
  int nc  = blockIdx.x;
  int tid = threadIdx.x;
  const float* s0 = covp + (size_t)nc * 192;
  const float* s1 = covp + ((size_t)NBATCH * NCLS + nc) * 192;
  __shared__ double lc[81], pc[81], plc[81], mla[9], mpr[9];
  const double Minv = 1.0 / (double)MM;
#define LDM(k) ((double)s0[k] + (double)s1[k])

  if (tid < 9)       mla[tid]     = LDM(tid) * Minv;
  else if (tid < 18) mpr[tid - 9] = LDM(tid) * Minv;
  __syncthreads();

  for (int e = tid; e < 81; e += 64) {
    int r = e / 9, c = e - 9 * (e / 9);
    int lo = r < c ? r : c, hi = r < c ? c : r;
    int k = lo * 9 - lo * (lo - 1) / 2 + (hi - lo);
    double a = LDM(18 + k) * Minv - mla[r] * mla[c];
    if (r == c) a += 1e-5;
    lc[e] = a;
    pc[e] = LDM(63 + k) * Minv - mpr[r] * mpr[c];
    plc[e] = LDM(108 + e) * Minv - mpr[r] * mla[c];
  }
  __syncthreads();

  // Cholesky of lc (lower), column-by-column
  for (int j = 0; j < 9; ++j) {
    if (tid == 0) lc[j * 9 + j] = sqrt(lc[j * 9 + j]);
    __syncthreads();
    if (tid > j && tid < 9) lc[tid * 9 + j] /= lc[j * 9 + j];
    __syncthreads();
    if (tid > j && tid < 9) {
      double lij = lc[tid * 9 + j];
      for (int k = j + 1; k <= tid; ++k) lc[tid * 9 + k] -= lij * lc[k * 9 + j];
    }
    __syncthreads();
  }

  // Solve W * L1^T = plc (row d per lane), in place
  if (tid < 9) {
    int d = tid;
    for (int j = 0; j < 9; ++j) {
      double t = plc[d * 9 + j];
      for (int k = 0; k < j; ++k) t -= plc[d * 9 + k] * lc[j * 9 + k];
      plc[d * 9 + j] = t / lc[j * 9 + j];
    }
  }
  __syncthreads();

  // A = pc - W W^T + 1e-6 I (in place in pc)
  for (int e = tid; e < 81; e += 64) {
    int r = e / 9, c = e - 9 * (e / 9);
    double a = pc[e];
    for (int f = 0; f < 9; ++f) a -= plc[r * 9 + f] * plc[c * 9 + f];
    if (r == c) a += 1e-6;
    pc[e] = a;
  }
  __syncthreads();

  // Cholesky of pc
  for (int j = 0; j < 9; ++j) {
    if (tid == 0) pc[j * 9 + j] = sqrt(pc[j * 9 + j]);
    __syncthreads();
    if (tid > j && tid < 9) pc[tid * 9 + j] /= pc[j * 9 + j];
    __syncthreads();
    if (tid > j && tid < 9) {
      double lij = pc[tid * 9 + j];
      for (int k = j + 1; k <= tid; ++k) pc[tid * 9 + k] -= lij * pc[k * 9 + j];
    }
    __syncthreads();
  }

  if (tid == 0) {
    double sl = 0.0;
    for (int j = 0; j < 9; ++j) sl += log(pc[j * 9 + j] + 1e-8);
    *(double*)(covp + (size_t)nc * 192 + 190) = sl;  // rmi_{n,c}
  }
#undef LDM
}

// ---------------------------------------------------------------------------
// Stage 4: reduce 76 fp64 partials -> out[0] = sum / (N * NUM_CLASSES)
// ---------------------------------------------------------------------------
__global__ __launch_bounds__(64) void stage4_reduce(
    const float* __restrict__ covp, float* __restrict__ out) {
  int tid = threadIdx.x;
  double v = 0.0;
  if (tid < NBATCH * NCLS)
    v = *(const double*)(covp + (size_t)tid * 192 + 190);
  if (tid + 64 < NBATCH * NCLS)
    v += *(const double*)(covp + (size_t)(tid + 64) * 192 + 190);
#pragma unroll
  for (int o = 32; o > 0; o >>= 1) v += __shfl_down(v, o, 64);
  if (tid == 0) out[0] = (float)(v / (double)(NBATCH * NCLS));
}

// ---------------------------------------------------------------------------
extern "C" void kernel_launch(void* const* d_in, const int* in_sizes, int n_in,
                              void* d_out, int out_size, void* d_ws, size_t ws_size,
                              hipStream_t stream) {
  const float* cls  = (const float*)d_in[0];
  const int* label  = (const int*)d_in[1];
  float* out = (float*)d_out;

  float* P    = (float*)d_ws;                              // 76*30096 f32
  float* L    = P + (size_t)NBATCH * NCLS * PP2A;          // 76*30096 f32
  float* covp = L + (size_t)NBATCH * NCLS * PP2A;          // ZS*76*192 f32

  stage1_pool<<<NBATCH * PH, 512, 0, stream>>>(cls, label, P, L);
  dim3 g2(NBATCH * NCLS, 3, ZS);
  stage2_mom<<<g2, 512, 0, stream>>>(P, L, covp);
  stage3_rmi<<<NBATCH * NCLS, 64, 0, stream>>>(covp);
  stage4_reduce<<<1, 64, 0, stream>>>(covp, out);
}

// Round 8
// 76.285 us; speedup vs baseline: 1.1223x; 1.1223x over previous
//
#include <hip/hip_runtime.h>
#include <math.h>

// Problem constants
#define NBATCH 4
#define NCLS   19
#define HWDIM  512
#define HW     (512 * 512)      // 262144
#define PH     171              // pooled H=W
#define PHP    176              // padded row stride (16B-aligned rows)
#define PP2A   (171 * 176)      // 30096 floats per (n,c) plane
#define NHW    169              // PH - radius + 1
#define MM     (169 * 169)      // 28561

typedef float f4  __attribute__((ext_vector_type(4)));
typedef float f2v __attribute__((ext_vector_type(2)));

// ---------------------------------------------------------------------------
// Stage 1 (round-6 proven version, unchanged): fused softmax + one-hot +
// 3x3/stride-3 avg-pool. One block per (n, pooled-row ph); thread = column.
// ---------------------------------------------------------------------------
__global__ __launch_bounds__(512) void stage1_pool(
    const float* __restrict__ cls, const int* __restrict__ label,
    float* __restrict__ P, float* __restrict__ L) {
  int n  = blockIdx.x / PH;
  int ph = blockIdx.x - n * PH;
  int col = threadIdx.x;  // input column 0..511

  float accP[NCLS], accL[NCLS];
#pragma unroll
  for (int c = 0; c < NCLS; ++c) { accP[c] = 0.f; accL[c] = 0.f; }

#pragma unroll
  for (int i = 0; i < 3; ++i) {
    int r = 3 * ph - 1 + i;
    if (r < 0 || r >= HWDIM) continue;
    int lb = label[((size_t)n * HWDIM + r) * HWDIM + col];
    const float* base = cls + (size_t)n * NCLS * HW + (size_t)r * HWDIM + col;
    float v[NCLS];
    float mx = -INFINITY;
#pragma unroll
    for (int c = 0; c < NCLS; ++c) {
      v[c] = base[(size_t)c * HW];
      mx = fmaxf(mx, v[c]);
    }
    float se = 0.f;
#pragma unroll
    for (int c = 0; c < NCLS; ++c) {
      v[c] = expf(v[c] - mx);
      se += v[c];
    }
    if (lb >= 0 && lb < NCLS) {
      float inv = 1.f / se;
#pragma unroll
      for (int c = 0; c < NCLS; ++c) {
        accP[c] += v[c] * inv;
        accL[c] += (lb == c) ? 1.f : 0.f;
      }
    }
  }

  __shared__ float xbP[4][516];
  __shared__ float xbL[4][516];
  const float inv9 = 1.f / 9.f;
#pragma unroll
  for (int c0 = 0; c0 < NCLS; c0 += 4) {
    int nc_round = (NCLS - c0) < 4 ? (NCLS - c0) : 4;
#pragma unroll
    for (int cc = 0; cc < 4; ++cc) {
      if (cc < nc_round) {
        xbP[cc][1 + col] = accP[(c0 + cc) < NCLS ? (c0 + cc) : 0];
        xbL[cc][1 + col] = accL[(c0 + cc) < NCLS ? (c0 + cc) : 0];
        if (col == 0) { xbP[cc][0] = 0.f; xbL[cc][0] = 0.f; }
      }
    }
    __syncthreads();
    if (col < PH) {
      int pw = col;
#pragma unroll
      for (int cc = 0; cc < 4; ++cc) {
        if (cc < nc_round) {
          int c = c0 + cc;
          float sP = xbP[cc][3 * pw] + xbP[cc][3 * pw + 1] + xbP[cc][3 * pw + 2];
          float sL = xbL[cc][3 * pw] + xbL[cc][3 * pw + 1] + xbL[cc][3 * pw + 2];
          size_t o = ((size_t)(n * NCLS + c)) * PP2A + (size_t)ph * PHP + pw;
          P[o] = sP * inv9;
          L[o] = sL * inv9;
        }
      }
    } else if (col < PHP) {
#pragma unroll
      for (int cc = 0; cc < 4; ++cc) {
        if (cc < nc_round) {
          int c = c0 + cc;
          size_t o = ((size_t)(n * NCLS + c)) * PP2A + (size_t)ph * PHP + col;
          P[o] = 0.f;
          L[o] = 0.f;
        }
      }
    }
    __syncthreads();
  }
}

// ---------------------------------------------------------------------------
// Stage 2: packed-fp32 moment accumulation (v_pk_fma_f32 via f2 ext-vectors).
// Parts: y==0 A: la*la ut45 + sum(la)  (la plane only)
//        y==1 B: pr*pr ut45 + sum(pr)  (pr plane only)
//        y==2 C: pr[d]*la[e] 81        (both planes)
// acc2[k] holds (even-x, odd-x) position partials; merged at epilogue.
// Ragged column 168 handled by dedicated tail threads (no divergent branch
// in full-strip waves). Record layout per nc, stride 192 floats:
//   [0..8] sum la | [9..17] sum pr | [18..62] la*la | [63..107] pr*pr
//   [108..188] pr*la | [190..191] (double) logdet from stage3
// ---------------------------------------------------------------------------
template <int MODE, int NA>
__device__ __forceinline__ void epilogue(const f2v (&acc2)[NA], float* red,
                                         float* __restrict__ covp, int nc) {
  int lane = threadIdx.x & 63;
  int wid  = threadIdx.x >> 6;  // 8 waves
#pragma unroll
  for (int k = 0; k < NA; ++k) {
    float v = acc2[k].x + acc2[k].y;
    v += __shfl_down(v, 32, 64);
    v += __shfl_down(v, 16, 64);
    v += __shfl_down(v, 8, 64);
    if (lane < 8) red[(wid * 8 + lane) * 84 + k] = v;
  }
  __syncthreads();
  int tid = threadIdx.x;
  if (tid < NA) {
    float sm = 0.f;
#pragma unroll
    for (int w = 0; w < 64; ++w) sm += red[w * 84 + tid];
    int off;
    if (MODE == 0)      off = (tid < 9) ? tid : 18 + (tid - 9);
    else if (MODE == 1) off = (tid < 9) ? 9 + tid : 63 + (tid - 9);
    else                off = 108 + tid;
    covp[(size_t)nc * 192 + off] = sm;
  }
}

// ---- A/B: self moments on one plane. Strips of 4 cols (pairs (0,1),(2,3)),
//      42 strips x 11 bands = 462 full tasks + 11 tail tasks (col 168). ----
template <int MODE>
__device__ __forceinline__ void mom_self(const float* __restrict__ X,
                                         float* __restrict__ covp, int nc,
                                         float* red) {
  f2v acc2[54];
#pragma unroll
  for (int k = 0; k < 54; ++k) acc2[k] = (f2v){0.f, 0.f};

  int tid = threadIdx.x;
  if (tid < 462) {
    int b = tid / 42, s = tid - b * 42;
    int x0 = 4 * s;                       // 0..164; positions x0..x0+3 <= 167
    int y0 = (NHW * b) / 11;
    int y1 = (NHW * (b + 1)) / 11;

    // window rows: w[r] = {c01, c12, c23, c34, c45} (f2 pairs, cols x0..x0+5)
    f2v w[3][5];
#pragma unroll
    for (int r = 0; r < 3; ++r) {
      f4  a  = *(const f4*)(X + (y0 + r) * PHP + x0);
      f2v bb = *(const f2v*)(X + (y0 + r) * PHP + x0 + 4);
      w[r][0] = (f2v){a.x, a.y}; w[r][1] = (f2v){a.y, a.z};
      w[r][2] = (f2v){a.z, a.w}; w[r][3] = (f2v){a.w, bb.x};
      w[r][4] = bb;
    }

    for (int y = y0; y < y1; ++y) {
      int yn = (y + 3 <= PH - 1) ? (y + 3) : (PH - 1);
      f4  a  = *(const f4*)(X + yn * PHP + x0);
      f2v bb = *(const f2v*)(X + yn * PHP + x0 + 4);

      // sums: V01(d)=w[dy][dx], V23(d)=w[dy][dx+2]
#pragma unroll
      for (int d = 0; d < 9; ++d) {
        acc2[d] += w[d / 3][d % 3];
        acc2[d] += w[d / 3][(d % 3) + 2];
      }
      // upper-tri products
      {
        int k = 9;
#pragma unroll
        for (int d = 0; d < 9; ++d)
#pragma unroll
          for (int e = d; e < 9; ++e) {
            acc2[k] += w[d / 3][d % 3] * w[e / 3][e % 3];
            acc2[k] += w[d / 3][(d % 3) + 2] * w[e / 3][(e % 3) + 2];
            ++k;
          }
      }
      // shift + commit prefetch
#pragma unroll
      for (int j = 0; j < 5; ++j) { w[0][j] = w[1][j]; w[1][j] = w[2][j]; }
      w[2][0] = (f2v){a.x, a.y}; w[2][1] = (f2v){a.y, a.z};
      w[2][2] = (f2v){a.z, a.w}; w[2][3] = (f2v){a.w, bb.x};
      w[2][4] = bb;
    }
  } else if (tid < 473) {  // tail: single position x=168 (scalar, .x half)
    int b  = tid - 462;
    int y0 = (NHW * b) / 11;
    int y1 = (NHW * (b + 1)) / 11;
    float t[3][3];
#pragma unroll
    for (int r = 0; r < 3; ++r)
#pragma unroll
      for (int c = 0; c < 3; ++c) t[r][c] = X[(y0 + r) * PHP + 168 + c];
    for (int y = y0; y < y1; ++y) {
      int yn = (y + 3 <= PH - 1) ? (y + 3) : (PH - 1);
      float n0 = X[yn * PHP + 168], n1 = X[yn * PHP + 169],
            n2 = X[yn * PHP + 170];
#pragma unroll
      for (int d = 0; d < 9; ++d) acc2[d].x += t[d / 3][d % 3];
      {
        int k = 9;
#pragma unroll
        for (int d = 0; d < 9; ++d)
#pragma unroll
          for (int e = d; e < 9; ++e) {
            acc2[k].x += t[d / 3][d % 3] * t[e / 3][e % 3];
            ++k;
          }
      }
#pragma unroll
      for (int c = 0; c < 3; ++c) { t[0][c] = t[1][c]; t[1][c] = t[2][c]; }
      t[2][0] = n0; t[2][1] = n1; t[2][2] = n2;
    }
  }
  epilogue<MODE, 54>(acc2, red, covp, nc);
}

// ---- C: cross moments pr[d]*la[e]. Strips of 2 cols (one packed pair),
//      84 strips x 6 bands = 504 full tasks + 6 tail tasks. ----
__device__ __forceinline__ void mom_cross(const float* __restrict__ Pp,
                                          const float* __restrict__ Lp,
                                          float* __restrict__ covp, int nc,
                                          float* red) {
  f2v acc2[81];
#pragma unroll
  for (int k = 0; k < 81; ++k) acc2[k] = (f2v){0.f, 0.f};

  int tid = threadIdx.x;
  if (tid < 504) {
    int b = tid / 84, s = tid - b * 84;
    int x0 = 2 * s;                       // 0..166; positions x0, x0+1
    int y0 = (NHW * b) / 6;
    int y1 = (NHW * (b + 1)) / 6;

    // w[r] = {c01, c12, c23} per plane (8B-aligned f2 loads)
    f2v wp[3][3], wl[3][3];
#pragma unroll
    for (int r = 0; r < 3; ++r) {
      f2v p01 = *(const f2v*)(Pp + (y0 + r) * PHP + x0);
      f2v p23 = *(const f2v*)(Pp + (y0 + r) * PHP + x0 + 2);
      wp[r][0] = p01; wp[r][1] = (f2v){p01.y, p23.x}; wp[r][2] = p23;
      f2v l01 = *(const f2v*)(Lp + (y0 + r) * PHP + x0);
      f2v l23 = *(const f2v*)(Lp + (y0 + r) * PHP + x0 + 2);
      wl[r][0] = l01; wl[r][1] = (f2v){l01.y, l23.x}; wl[r][2] = l23;
    }

    for (int y = y0; y < y1; ++y) {
      int yn = (y + 3 <= PH - 1) ? (y + 3) : (PH - 1);
      f2v p01 = *(const f2v*)(Pp + yn * PHP + x0);
      f2v p23 = *(const f2v*)(Pp + yn * PHP + x0 + 2);
      f2v l01 = *(const f2v*)(Lp + yn * PHP + x0);
      f2v l23 = *(const f2v*)(Lp + yn * PHP + x0 + 2);

#pragma unroll
      for (int d = 0; d < 9; ++d)
#pragma unroll
        for (int e = 0; e < 9; ++e)
          acc2[d * 9 + e] += wp[d / 3][d % 3] * wl[e / 3][e % 3];

#pragma unroll
      for (int j = 0; j < 3; ++j) {
        wp[0][j] = wp[1][j]; wp[1][j] = wp[2][j];
        wl[0][j] = wl[1][j]; wl[1][j] = wl[2][j];
      }
      wp[2][0] = p01; wp[2][1] = (f2v){p01.y, p23.x}; wp[2][2] = p23;
      wl[2][0] = l01; wl[2][1] = (f2v){l01.y, l23.x}; wl[2][2] = l23;
    }
  } else if (tid < 510) {  // tail: position x=168 (scalar)
    int b  = tid - 504;
    int y0 = (NHW * b) / 6;
    int y1 = (NHW * (b + 1)) / 6;
    float tp[3][3], tl[3][3];
#pragma unroll
    for (int r = 0; r < 3; ++r)
#pragma unroll
      for (int c = 0; c < 3; ++c) {
        tp[r][c] = Pp[(y0 + r) * PHP + 168 + c];
        tl[r][c] = Lp[(y0 + r) * PHP + 168 + c];
      }
    for (int y = y0; y < y1; ++y) {
      int yn = (y + 3 <= PH - 1) ? (y + 3) : (PH - 1);
      float np0 = Pp[yn * PHP + 168], np1 = Pp[yn * PHP + 169],
            np2 = Pp[yn * PHP + 170];
      float nl0 = Lp[yn * PHP + 168], nl1 = Lp[yn * PHP + 169],
            nl2 = Lp[yn * PHP + 170];
#pragma unroll
      for (int d = 0; d < 9; ++d)
#pragma unroll
        for (int e = 0; e < 9; ++e)
          acc2[d * 9 + e].x += tp[d / 3][d % 3] * tl[e / 3][e % 3];
#pragma unroll
      for (int c = 0; c < 3; ++c) {
        tp[0][c] = tp[1][c]; tp[1][c] = tp[2][c];
        tl[0][c] = tl[1][c]; tl[1][c] = tl[2][c];
      }
      tp[2][0] = np0; tp[2][1] = np1; tp[2][2] = np2;
      tl[2][0] = nl0; tl[2][1] = nl1; tl[2][2] = nl2;
    }
  }
  epilogue<2, 81>(acc2, red, covp, nc);
}

__global__ __launch_bounds__(512) void stage2_mom(
    const float* __restrict__ P, const float* __restrict__ L,
    float* __restrict__ covp) {
  __shared__ float red[64 * 84];  // 21.5 KB
  int nc = blockIdx.x;
  const float* Pp = P + (size_t)nc * PP2A;
  const float* Lp = L + (size_t)nc * PP2A;
  if (blockIdx.y == 0)      mom_self<0>(Lp, covp, nc, red);
  else if (blockIdx.y == 1) mom_self<1>(Pp, covp, nc, red);
  else                      mom_cross(Pp, Lp, covp, nc, red);
}

// ---------------------------------------------------------------------------
// Stage 3 (round-6 proven, single record): fp64 in LDS, Cholesky(la_cov+1e-5),
// triangular solve, Schur + 1e-6 I, Cholesky logdet -> covp[nc*192+190..191].
// ---------------------------------------------------------------------------
__global__ __launch_bounds__(64) void stage3_rmi(float* __restrict__ covp) {
  int nc  = blockIdx.x;
  int tid = threadIdx.x;
  const float* s = covp + (size_t)nc * 192;
  __shared__ double lc[81], pc[81], plc[81], mla[9], mpr[9];
  const double Minv = 1.0 / (double)MM;

  if (tid < 9)       mla[tid]     = (double)s[tid] * Minv;
  else if (tid < 18) mpr[tid - 9] = (double)s[tid] * Minv;
  __syncthreads();

  for (int e = tid; e < 81; e += 64) {
    int r = e / 9, c = e - 9 * (e / 9);
    int lo = r < c ? r : c, hi = r < c ? c : r;
    int k = lo * 9 - lo * (lo - 1) / 2 + (hi - lo);
    double a = (double)s[18 + k] * Minv - mla[r] * mla[c];
    if (r == c) a += 1e-5;
    lc[e] = a;
    pc[e] = (double)s[63 + k] * Minv - mpr[r] * mpr[c];
    plc[e] = (double)s[108 + e] * Minv - mpr[r] * mla[c];
  }
  __syncthreads();

  for (int j = 0; j < 9; ++j) {
    if (tid == 0) lc[j * 9 + j] = sqrt(lc[j * 9 + j]);
    __syncthreads();
    if (tid > j && tid < 9) lc[tid * 9 + j] /= lc[j * 9 + j];
    __syncthreads();
    if (tid > j && tid < 9) {
      double lij = lc[tid * 9 + j];
      for (int k = j + 1; k <= tid; ++k) lc[tid * 9 + k] -= lij * lc[k * 9 + j];
    }
    __syncthreads();
  }

  if (tid < 9) {
    int d = tid;
    for (int j = 0; j < 9; ++j) {
      double t = plc[d * 9 + j];
      for (int k = 0; k < j; ++k) t -= plc[d * 9 + k] * lc[j * 9 + k];
      plc[d * 9 + j] = t / lc[j * 9 + j];
    }
  }
  __syncthreads();

  for (int e = tid; e < 81; e += 64) {
    int r = e / 9, c = e - 9 * (e / 9);
    double a = pc[e];
    for (int f = 0; f < 9; ++f) a -= plc[r * 9 + f] * plc[c * 9 + f];
    if (r == c) a += 1e-6;
    pc[e] = a;
  }
  __syncthreads();

  for (int j = 0; j < 9; ++j) {
    if (tid == 0) pc[j * 9 + j] = sqrt(pc[j * 9 + j]);
    __syncthreads();
    if (tid > j && tid < 9) pc[tid * 9 + j] /= pc[j * 9 + j];
    __syncthreads();
    if (tid > j && tid < 9) {
      double lij = pc[tid * 9 + j];
      for (int k = j + 1; k <= tid; ++k) pc[tid * 9 + k] -= lij * pc[k * 9 + j];
    }
    __syncthreads();
  }

  if (tid == 0) {
    double sl = 0.0;
    for (int j = 0; j < 9; ++j) sl += log(pc[j * 9 + j] + 1e-8);
    *(double*)(covp + (size_t)nc * 192 + 190) = sl;  // rmi_{n,c}
  }
}

// ---------------------------------------------------------------------------
// Stage 4: reduce 76 fp64 partials -> out[0] = sum / (N * NUM_CLASSES)
// ---------------------------------------------------------------------------
__global__ __launch_bounds__(64) void stage4_reduce(
    const float* __restrict__ covp, float* __restrict__ out) {
  int tid = threadIdx.x;
  double v = 0.0;
  if (tid < NBATCH * NCLS)
    v = *(const double*)(covp + (size_t)tid * 192 + 190);
  if (tid + 64 < NBATCH * NCLS)
    v += *(const double*)(covp + (size_t)(tid + 64) * 192 + 190);
#pragma unroll
  for (int o = 32; o > 0; o >>= 1) v += __shfl_down(v, o, 64);
  if (tid == 0) out[0] = (float)(v / (double)(NBATCH * NCLS));
}

// ---------------------------------------------------------------------------
extern "C" void kernel_launch(void* const* d_in, const int* in_sizes, int n_in,
                              void* d_out, int out_size, void* d_ws, size_t ws_size,
                              hipStream_t stream) {
  const float* cls  = (const float*)d_in[0];
  const int* label  = (const int*)d_in[1];
  float* out = (float*)d_out;

  float* P    = (float*)d_ws;                              // 76*30096 f32
  float* L    = P + (size_t)NBATCH * NCLS * PP2A;          // 76*30096 f32
  float* covp = L + (size_t)NBATCH * NCLS * PP2A;          // 76*192 f32

  stage1_pool<<<NBATCH * PH, 512, 0, stream>>>(cls, label, P, L);
  dim3 g2(NBATCH * NCLS, 3, 1);
  stage2_mom<<<g2, 512, 0, stream>>>(P, L, covp);
  stage3_rmi<<<NBATCH * NCLS, 64, 0, stream>>>(covp);
  stage4_reduce<<<1, 64, 0, stream>>>(covp, out);
}

// Round 9
// 72.488 us; speedup vs baseline: 1.1811x; 1.0524x over previous
//
#include <hip/hip_runtime.h>
#include <math.h>

// Problem constants
#define NBATCH 4
#define NCLS   19
#define HWDIM  512
#define HW     (512 * 512)      // 262144
#define PH     171              // pooled H=W
#define PHP    176              // padded row stride (16B-aligned rows)
#define PP2A   (171 * 176)      // 30096 floats per (n,c) plane
#define NHW    169              // PH - radius + 1
#define MM     (169 * 169)      // 28561

typedef float f4  __attribute__((ext_vector_type(4)));
typedef float f2v __attribute__((ext_vector_type(2)));

// ---------------------------------------------------------------------------
// Stage 1 (round-6 measured version): fused softmax + one-hot + 3x3/stride-3
// avg-pool (pad=1, /9). One block per (n, pooled-row ph); thread = column.
// ALL 57 cls + 3 label loads hoisted before any math; __expf; x-pool via LDS
// in 2 rounds of 10 classes. Output row stride PHP=176, pad cols zeroed.
// ---------------------------------------------------------------------------
__global__ __launch_bounds__(512) void stage1_pool(
    const float* __restrict__ cls, const int* __restrict__ label,
    float* __restrict__ P, float* __restrict__ L) {
  int n  = blockIdx.x / PH;
  int ph = blockIdx.x - n * PH;
  int col = threadIdx.x;  // input column 0..511

  float vv[3][NCLS];
  int lbs[3];
#pragma unroll
  for (int i = 0; i < 3; ++i) {
    int r = 3 * ph - 1 + i;
    bool ok = (r >= 0) && (r < HWDIM);  // wave-uniform
    if (ok) {
      lbs[i] = label[((size_t)n * HWDIM + r) * HWDIM + col];
      const float* base = cls + (size_t)n * NCLS * HW + (size_t)r * HWDIM + col;
#pragma unroll
      for (int c = 0; c < NCLS; ++c) vv[i][c] = base[(size_t)c * HW];
    } else {
      lbs[i] = -1;
#pragma unroll
      for (int c = 0; c < NCLS; ++c) vv[i][c] = 0.f;
    }
  }

  float accP[NCLS], accL[NCLS];
#pragma unroll
  for (int c = 0; c < NCLS; ++c) { accP[c] = 0.f; accL[c] = 0.f; }
#pragma unroll
  for (int i = 0; i < 3; ++i) {
    int lb = lbs[i];
    float mx = vv[i][0];
#pragma unroll
    for (int c = 1; c < NCLS; ++c) mx = fmaxf(mx, vv[i][c]);
    float se = 0.f;
    float ex[NCLS];
#pragma unroll
    for (int c = 0; c < NCLS; ++c) {
      ex[c] = __expf(vv[i][c] - mx);
      se += ex[c];
    }
    float m = (lb >= 0 && lb < NCLS) ? 1.f : 0.f;
    float inv = m / se;
#pragma unroll
    for (int c = 0; c < NCLS; ++c) {
      accP[c] += ex[c] * inv;
      accL[c] += (lb == c) ? 1.f : 0.f;  // compile-time index
    }
  }

  __shared__ float xbP[10][516];
  __shared__ float xbL[10][516];
  const float inv9 = 1.f / 9.f;
#pragma unroll
  for (int c0 = 0; c0 < NCLS; c0 += 10) {
#pragma unroll
    for (int cc = 0; cc < 10; ++cc) {
      if (c0 + cc < NCLS) {
        xbP[cc][1 + col] = accP[(c0 + cc) < NCLS ? (c0 + cc) : 0];
        xbL[cc][1 + col] = accL[(c0 + cc) < NCLS ? (c0 + cc) : 0];
        if (col == 0) { xbP[cc][0] = 0.f; xbL[cc][0] = 0.f; }
      }
    }
    __syncthreads();
    if (col < PH) {
      int pw = col;
#pragma unroll
      for (int cc = 0; cc < 10; ++cc) {
        if (c0 + cc < NCLS) {
          int c = c0 + cc;
          float sP = xbP[cc][3 * pw] + xbP[cc][3 * pw + 1] + xbP[cc][3 * pw + 2];
          float sL = xbL[cc][3 * pw] + xbL[cc][3 * pw + 1] + xbL[cc][3 * pw + 2];
          size_t o = ((size_t)(n * NCLS + c)) * PP2A + (size_t)ph * PHP + pw;
          P[o] = sP * inv9;
          L[o] = sL * inv9;
        }
      }
    } else if (col < PHP) {
#pragma unroll
      for (int cc = 0; cc < 10; ++cc) {
        if (c0 + cc < NCLS) {
          int c = c0 + cc;
          size_t o = ((size_t)(n * NCLS + c)) * PP2A + (size_t)ph * PHP + col;
          P[o] = 0.f;
          L[o] = 0.f;
        }
      }
    }
    __syncthreads();
  }
}

// ---------------------------------------------------------------------------
// Stage 2: packed-fp32 moments with ZERO-MOVE 4-slot window rotation.
// Parts: y==0 A: la*la ut45 + sum(la) | y==1 B: pr*pr ut45 + sum(pr)
//        y==2 C: pr[d]*la[e] (81)
// acc2[k] = (even-x, odd-x) packed partials, merged at epilogue.
// Record layout per nc (stride 192 f32):
//   [0..8] sum la | [9..17] sum pr | [18..62] la*la | [63..107] pr*pr
//   [108..188] pr*la | [190..191] (double) logdet from stage3
// ---------------------------------------------------------------------------
template <int MODE, int NA>
__device__ __forceinline__ void epilogue(const f2v (&acc2)[NA], float* red,
                                         float* __restrict__ covp, int nc) {
  int lane = threadIdx.x & 63;
  int wid  = threadIdx.x >> 6;  // 8 waves
#pragma unroll
  for (int k = 0; k < NA; ++k) {
    float v = acc2[k].x + acc2[k].y;
    v += __shfl_down(v, 32, 64);
    v += __shfl_down(v, 16, 64);
    v += __shfl_down(v, 8, 64);
    if (lane < 8) red[(wid * 8 + lane) * 84 + k] = v;
  }
  __syncthreads();
  int tid = threadIdx.x;
  if (tid < NA) {
    float sm = 0.f;
#pragma unroll
    for (int w = 0; w < 64; ++w) sm += red[w * 84 + tid];
    int off;
    if (MODE == 0)      off = (tid < 9) ? tid : 18 + (tid - 9);
    else if (MODE == 1) off = (tid < 9) ? 9 + tid : 63 + (tid - 9);
    else                off = 108 + tid;
    covp[(size_t)nc * 192 + off] = sm;
  }
}

// row-pair accessor helpers (fold to direct refs under full unroll)
__device__ __forceinline__ void fma_self_triple(f2v (&acc2)[54],
    const f2v (&r0)[5], const f2v (&r1)[5], const f2v (&r2)[5]) {
#define RP(d, off) ((d) < 3 ? r0[(d) % 3 + (off)] \
                 : (d) < 6 ? r1[(d) % 3 + (off)] : r2[(d) % 3 + (off)])
#pragma unroll
  for (int d = 0; d < 9; ++d) {
    acc2[d] += RP(d, 0);
    acc2[d] += RP(d, 2);
  }
  {
    int k = 9;
#pragma unroll
    for (int d = 0; d < 9; ++d)
#pragma unroll
      for (int e = d; e < 9; ++e) {
        acc2[k] += RP(d, 0) * RP(e, 0);
        acc2[k] += RP(d, 2) * RP(e, 2);
        ++k;
      }
  }
#undef RP
}

__device__ __forceinline__ void fma_cross_triple(f2v (&acc2)[81],
    const f2v (&p0)[3], const f2v (&p1)[3], const f2v (&p2)[3],
    const f2v (&l0)[3], const f2v (&l1)[3], const f2v (&l2)[3]) {
#define QP(d) ((d) < 3 ? p0[(d) % 3] : (d) < 6 ? p1[(d) % 3] : p2[(d) % 3])
#define QL(e) ((e) < 3 ? l0[(e) % 3] : (e) < 6 ? l1[(e) % 3] : l2[(e) % 3])
#pragma unroll
  for (int d = 0; d < 9; ++d)
#pragma unroll
    for (int e = 0; e < 9; ++e)
      acc2[d * 9 + e] += QP(d) * QL(e);
#undef QP
#undef QL
}

// ---- A/B: self moments, strips of 4 positions; 42x11 full + 11 tail ----
template <int MODE>
__device__ __forceinline__ void mom_self(const float* __restrict__ X,
                                         float* __restrict__ covp, int nc,
                                         float* red) {
  f2v acc2[54];
#pragma unroll
  for (int k = 0; k < 54; ++k) acc2[k] = (f2v){0.f, 0.f};

  int tid = threadIdx.x;
  if (tid < 462) {
    int b = tid / 42, s = tid - b * 42;
    int x0 = 4 * s;  // 0..164
    int y0 = (NHW * b) / 11;
    int y1 = (NHW * (b + 1)) / 11;

    f2v s0[5], s1[5], s2[5], s3[5];
    auto ldr = [&](f2v (&dst)[5], int row) {
      if (row > PH - 1) row = PH - 1;  // clamp; clamped rows never consumed
      f4  a  = *(const f4*)(X + row * PHP + x0);
      f2v bb = *(const f2v*)(X + row * PHP + x0 + 4);
      dst[0] = (f2v){a.x, a.y}; dst[1] = (f2v){a.y, a.z};
      dst[2] = (f2v){a.z, a.w}; dst[3] = (f2v){a.w, bb.x};
      dst[4] = bb;
    };
    ldr(s0, y0); ldr(s1, y0 + 1); ldr(s2, y0 + 2);

    int y = y0;
    int span = y1 - y0;
    int nf = span & ~3;
    for (int i = 0; i < nf; i += 4, y += 4) {
      ldr(s3, y + 3); fma_self_triple(acc2, s0, s1, s2);
      ldr(s0, y + 4); fma_self_triple(acc2, s1, s2, s3);
      ldr(s1, y + 5); fma_self_triple(acc2, s2, s3, s0);
      ldr(s2, y + 6); fma_self_triple(acc2, s3, s0, s1);
    }
    int r = span & 3;
    if (r > 0) { ldr(s3, y + 3); fma_self_triple(acc2, s0, s1, s2); ++y; }
    if (r > 1) { ldr(s0, y + 3); fma_self_triple(acc2, s1, s2, s3); ++y; }
    if (r > 2) { ldr(s1, y + 3); fma_self_triple(acc2, s2, s3, s0); ++y; }
  } else if (tid < 473) {  // tail: single position x=168 (scalar, .x half)
    int b  = tid - 462;
    int y0 = (NHW * b) / 11;
    int y1 = (NHW * (b + 1)) / 11;
    float t[3][3];
#pragma unroll
    for (int r = 0; r < 3; ++r)
#pragma unroll
      for (int c = 0; c < 3; ++c) t[r][c] = X[(y0 + r) * PHP + 168 + c];
    for (int y = y0; y < y1; ++y) {
      int yn = (y + 3 <= PH - 1) ? (y + 3) : (PH - 1);
      float n0 = X[yn * PHP + 168], n1 = X[yn * PHP + 169],
            n2 = X[yn * PHP + 170];
#pragma unroll
      for (int d = 0; d < 9; ++d) acc2[d].x += t[d / 3][d % 3];
      {
        int k = 9;
#pragma unroll
        for (int d = 0; d < 9; ++d)
#pragma unroll
          for (int e = d; e < 9; ++e) {
            acc2[k].x += t[d / 3][d % 3] * t[e / 3][e % 3];
            ++k;
          }
      }
#pragma unroll
      for (int c = 0; c < 3; ++c) { t[0][c] = t[1][c]; t[1][c] = t[2][c]; }
      t[2][0] = n0; t[2][1] = n1; t[2][2] = n2;
    }
  }
  epilogue<MODE, 54>(acc2, red, covp, nc);
}

// ---- C: cross moments, strips of 2 positions; 84x6 full + 6 tail ----
__device__ __forceinline__ void mom_cross(const float* __restrict__ Pp,
                                          const float* __restrict__ Lp,
                                          float* __restrict__ covp, int nc,
                                          float* red) {
  f2v acc2[81];
#pragma unroll
  for (int k = 0; k < 81; ++k) acc2[k] = (f2v){0.f, 0.f};

  int tid = threadIdx.x;
  if (tid < 504) {
    int b = tid / 84, s = tid - b * 84;
    int x0 = 2 * s;  // 0..166
    int y0 = (NHW * b) / 6;
    int y1 = (NHW * (b + 1)) / 6;

    f2v p0[3], p1[3], p2[3], p3[3];
    f2v l0[3], l1[3], l2[3], l3[3];
    auto ldc = [&](f2v (&dp)[3], f2v (&dl)[3], int row) {
      if (row > PH - 1) row = PH - 1;
      f2v a = *(const f2v*)(Pp + row * PHP + x0);
      f2v bb = *(const f2v*)(Pp + row * PHP + x0 + 2);
      dp[0] = a; dp[1] = (f2v){a.y, bb.x}; dp[2] = bb;
      f2v c = *(const f2v*)(Lp + row * PHP + x0);
      f2v d = *(const f2v*)(Lp + row * PHP + x0 + 2);
      dl[0] = c; dl[1] = (f2v){c.y, d.x}; dl[2] = d;
    };
    ldc(p0, l0, y0); ldc(p1, l1, y0 + 1); ldc(p2, l2, y0 + 2);

    int y = y0;
    int span = y1 - y0;
    int nf = span & ~3;
    for (int i = 0; i < nf; i += 4, y += 4) {
      ldc(p3, l3, y + 3); fma_cross_triple(acc2, p0, p1, p2, l0, l1, l2);
      ldc(p0, l0, y + 4); fma_cross_triple(acc2, p1, p2, p3, l1, l2, l3);
      ldc(p1, l1, y + 5); fma_cross_triple(acc2, p2, p3, p0, l2, l3, l0);
      ldc(p2, l2, y + 6); fma_cross_triple(acc2, p3, p0, p1, l3, l0, l1);
    }
    int r = span & 3;
    if (r > 0) { ldc(p3, l3, y + 3); fma_cross_triple(acc2, p0, p1, p2, l0, l1, l2); ++y; }
    if (r > 1) { ldc(p0, l0, y + 3); fma_cross_triple(acc2, p1, p2, p3, l1, l2, l3); ++y; }
    if (r > 2) { ldc(p1, l1, y + 3); fma_cross_triple(acc2, p2, p3, p0, l2, l3, l0); ++y; }
  } else if (tid < 510) {  // tail: position x=168 (scalar)
    int b  = tid - 504;
    int y0 = (NHW * b) / 6;
    int y1 = (NHW * (b + 1)) / 6;
    float tp[3][3], tl[3][3];
#pragma unroll
    for (int r = 0; r < 3; ++r)
#pragma unroll
      for (int c = 0; c < 3; ++c) {
        tp[r][c] = Pp[(y0 + r) * PHP + 168 + c];
        tl[r][c] = Lp[(y0 + r) * PHP + 168 + c];
      }
    for (int y = y0; y < y1; ++y) {
      int yn = (y + 3 <= PH - 1) ? (y + 3) : (PH - 1);
      float np0 = Pp[yn * PHP + 168], np1 = Pp[yn * PHP + 169],
            np2 = Pp[yn * PHP + 170];
      float nl0 = Lp[yn * PHP + 168], nl1 = Lp[yn * PHP + 169],
            nl2 = Lp[yn * PHP + 170];
#pragma unroll
      for (int d = 0; d < 9; ++d)
#pragma unroll
        for (int e = 0; e < 9; ++e)
          acc2[d * 9 + e].x += tp[d / 3][d % 3] * tl[e / 3][e % 3];
#pragma unroll
      for (int c = 0; c < 3; ++c) {
        tp[0][c] = tp[1][c]; tp[1][c] = tp[2][c];
        tl[0][c] = tl[1][c]; tl[1][c] = tl[2][c];
      }
      tp[2][0] = np0; tp[2][1] = np1; tp[2][2] = np2;
      tl[2][0] = nl0; tl[2][1] = nl1; tl[2][2] = nl2;
    }
  }
  epilogue<2, 81>(acc2, red, covp, nc);
}

__global__ __launch_bounds__(512) void stage2_mom(
    const float* __restrict__ P, const float* __restrict__ L,
    float* __restrict__ covp) {
  __shared__ float red[64 * 84];  // 21.5 KB
  int nc = blockIdx.x;
  const float* Pp = P + (size_t)nc * PP2A;
  const float* Lp = L + (size_t)nc * PP2A;
  if (blockIdx.y == 0)      mom_self<0>(Lp, covp, nc, red);
  else if (blockIdx.y == 1) mom_self<1>(Pp, covp, nc, red);
  else                      mom_cross(Pp, Lp, covp, nc, red);
}

// ---------------------------------------------------------------------------
// Stage 3: one 64-thread block per (n,c). fp64 in LDS: Cholesky(la_cov+1e-5),
// triangular solve, Schur + 1e-6 I, Cholesky logdet -> covp[nc*192+190..191].
// ---------------------------------------------------------------------------
__global__ __launch_bounds__(64) void stage3_rmi(float* __restrict__ covp) {
  int nc  = blockIdx.x;
  int tid = threadIdx.x;
  const float* s = covp + (size_t)nc * 192;
  __shared__ double lc[81], pc[81], plc[81], mla[9], mpr[9];
  const double Minv = 1.0 / (double)MM;

  if (tid < 9)       mla[tid]     = (double)s[tid] * Minv;
  else if (tid < 18) mpr[tid - 9] = (double)s[tid] * Minv;
  __syncthreads();

  for (int e = tid; e < 81; e += 64) {
    int r = e / 9, c = e - 9 * (e / 9);
    int lo = r < c ? r : c, hi = r < c ? c : r;
    int k = lo * 9 - lo * (lo - 1) / 2 + (hi - lo);
    double a = (double)s[18 + k] * Minv - mla[r] * mla[c];
    if (r == c) a += 1e-5;
    lc[e] = a;
    pc[e] = (double)s[63 + k] * Minv - mpr[r] * mpr[c];
    plc[e] = (double)s[108 + e] * Minv - mpr[r] * mla[c];
  }
  __syncthreads();

  for (int j = 0; j < 9; ++j) {
    if (tid == 0) lc[j * 9 + j] = sqrt(lc[j * 9 + j]);
    __syncthreads();
    if (tid > j && tid < 9) lc[tid * 9 + j] /= lc[j * 9 + j];
    __syncthreads();
    if (tid > j && tid < 9) {
      double lij = lc[tid * 9 + j];
      for (int k = j + 1; k <= tid; ++k) lc[tid * 9 + k] -= lij * lc[k * 9 + j];
    }
    __syncthreads();
  }

  if (tid < 9) {
    int d = tid;
    for (int j = 0; j < 9; ++j) {
      double t = plc[d * 9 + j];
      for (int k = 0; k < j; ++k) t -= plc[d * 9 + k] * lc[j * 9 + k];
      plc[d * 9 + j] = t / lc[j * 9 + j];
    }
  }
  __syncthreads();

  for (int e = tid; e < 81; e += 64) {
    int r = e / 9, c = e - 9 * (e / 9);
    double a = pc[e];
    for (int f = 0; f < 9; ++f) a -= plc[r * 9 + f] * plc[c * 9 + f];
    if (r == c) a += 1e-6;
    pc[e] = a;
  }
  __syncthreads();

  for (int j = 0; j < 9; ++j) {
    if (tid == 0) pc[j * 9 + j] = sqrt(pc[j * 9 + j]);
    __syncthreads();
    if (tid > j && tid < 9) pc[tid * 9 + j] /= pc[j * 9 + j];
    __syncthreads();
    if (tid > j && tid < 9) {
      double lij = pc[tid * 9 + j];
      for (int k = j + 1; k <= tid; ++k) pc[tid * 9 + k] -= lij * pc[k * 9 + j];
    }
    __syncthreads();
  }

  if (tid == 0) {
    double sl = 0.0;
    for (int j = 0; j < 9; ++j) sl += log(pc[j * 9 + j] + 1e-8);
    *(double*)(covp + (size_t)nc * 192 + 190) = sl;  // rmi_{n,c}
  }
}

// ---------------------------------------------------------------------------
// Stage 4: reduce 76 fp64 partials -> out[0] = sum / (N * NUM_CLASSES)
// ---------------------------------------------------------------------------
__global__ __launch_bounds__(64) void stage4_reduce(
    const float* __restrict__ covp, float* __restrict__ out) {
  int tid = threadIdx.x;
  double v = 0.0;
  if (tid < NBATCH * NCLS)
    v = *(const double*)(covp + (size_t)tid * 192 + 190);
  if (tid + 64 < NBATCH * NCLS)
    v += *(const double*)(covp + (size_t)(tid + 64) * 192 + 190);
#pragma unroll
  for (int o = 32; o > 0; o >>= 1) v += __shfl_down(v, o, 64);
  if (tid == 0) out[0] = (float)(v / (double)(NBATCH * NCLS));
}

// ---------------------------------------------------------------------------
extern "C" void kernel_launch(void* const* d_in, const int* in_sizes, int n_in,
                              void* d_out, int out_size, void* d_ws, size_t ws_size,
                              hipStream_t stream) {
  const float* cls  = (const float*)d_in[0];
  const int* label  = (const int*)d_in[1];
  float* out = (float*)d_out;

  float* P    = (float*)d_ws;                              // 76*30096 f32
  float* L    = P + (size_t)NBATCH * NCLS * PP2A;          // 76*30096 f32
  float* covp = L + (size_t)NBATCH * NCLS * PP2A;          // 76*192 f32

  stage1_pool<<<NBATCH * PH, 512, 0, stream>>>(cls, label, P, L);
  dim3 g2(NBATCH * NCLS, 3, 1);
  stage2_mom<<<g2, 512, 0, stream>>>(P, L, covp);
  stage3_rmi<<<NBATCH * NCLS, 64, 0, stream>>>(covp);
  stage4_reduce<<<1, 64, 0, stream>>>(covp, out);
}